// Round 1
// baseline (99.887 us; speedup 1.0000x reference)
//
#include <hip/hip_runtime.h>
#include <math.h>

// Both clouds: 16384 x float2.
#define NPTS  16384
#define BLK   256
#define Q     8                      // queries per thread
#define QB    (NPTS / (BLK * Q))     // 8 query-blocks per direction
#define TCH   128                    // target chunks per direction
#define CHUNK (NPTS / TCH)           // 128 targets per chunk
#define U     (CHUNK / 2)            // 64 target PAIRS per chunk

// ws layout (float): ws[ch][dir*NPTS + q] = per-chunk min d^2 for that query.
// TCH * 2*NPTS * 4 B = 16 MB of the 256 MB workspace. Every slot is written
// exactly once (block (dir,qb,ch) owns slots [ch][dir*NPTS + qb*2048 .. +2047]),
// so no initialization and no atomics are needed; the harness poison is
// overwritten before it is ever read.

__global__ __launch_bounds__(BLK, 6) void cc_min_kernel(
        const float2* __restrict__ pc,    // render points (16384)
        const float2* __restrict__ ref,   // ref points    (16384)
        float* __restrict__ ws,
        float* __restrict__ out) {
    // Pair-SoA: sxy[u] = (-2xa, -2ya, -2xb, -2yb), sz[u] = (|a|^2, |b|^2)
    __shared__ float4 sxy[U];
    __shared__ float2 sz[U];

    int b   = blockIdx.x;
    int dir = b / (QB * TCH);
    int rem = b % (QB * TCH);
    int qb  = rem / TCH;
    int ch  = rem % TCH;

    // Zero the output accumulator for the (stream-ordered) final kernel.
    if (b == 0 && threadIdx.x == 0) out[0] = 0.0f;

    const float2* __restrict__ qry = dir ? ref : pc;
    const float2* __restrict__ tgt = dir ? pc  : ref;

    if (threadIdx.x < U) {
        int u = threadIdx.x;
        float4 t2 = ((const float4*)tgt)[ch * U + u];  // (xa, ya, xb, yb)
        sxy[u] = make_float4(-2.0f * t2.x, -2.0f * t2.y,
                             -2.0f * t2.z, -2.0f * t2.w);
        sz[u] = make_float2(fmaf(t2.x, t2.x, t2.y * t2.y),
                            fmaf(t2.z, t2.z, t2.w * t2.w));
    }

    // Q queries per thread (coalesced, stride BLK)
    float px[Q], py[Q], pn[Q], m[Q];
    int qbase = qb * (BLK * Q) + threadIdx.x;
#pragma unroll
    for (int j = 0; j < Q; ++j) {
        float2 p = qry[qbase + j * BLK];
        px[j] = p.x;
        py[j] = p.y;
        pn[j] = fmaf(p.x, p.x, p.y * p.y);
        m[j]  = INFINITY;
    }
    __syncthreads();

    // Surrogate s = |t|^2 - 2q.t.  Per target-pair per query:
    //   4 FMA + 1 min3.
#pragma unroll 8
    for (int u = 0; u < U; ++u) {
        float4 xy = sxy[u];          // ds_read_b128 (broadcast)
        float2 z  = sz[u];           // ds_read_b64  (broadcast)
#pragma unroll
        for (int j = 0; j < Q; ++j) {
            float s1 = fmaf(px[j], xy.x, fmaf(py[j], xy.y, z.x));
            float s2 = fmaf(px[j], xy.z, fmaf(py[j], xy.w, z.y));
            m[j] = fminf(fminf(m[j], s1), s2);   // -> v_min3_f32
        }
    }

    // d^2 = max(min_surrogate + |p|^2, 0); plain coalesced store of this
    // block's partial min — combine happens in cc_final_kernel.
    float* wrow = ws + (size_t)ch * (2 * NPTS) + dir * NPTS + qbase;
#pragma unroll
    for (int j = 0; j < Q; ++j) {
        wrow[j * BLK] = fmaxf(m[j] + pn[j], 0.0f);
    }
}

// Parallel finish: one thread per (dir,query). 128-way min over chunks
// (coalesced, stride 2*NPTS floats), sqrt, wave reduce, one atomicAdd/wave.
__global__ __launch_bounds__(BLK) void cc_final_kernel(
        const float* __restrict__ ws, float* __restrict__ out) {
    int q = blockIdx.x * BLK + threadIdx.x;   // 0 .. 2*NPTS-1

    float m0 = INFINITY, m1 = INFINITY, m2 = INFINITY, m3 = INFINITY;
#pragma unroll 8
    for (int ch = 0; ch < TCH; ch += 4) {
        m0 = fminf(m0, ws[(size_t)(ch + 0) * (2 * NPTS) + q]);
        m1 = fminf(m1, ws[(size_t)(ch + 1) * (2 * NPTS) + q]);
        m2 = fminf(m2, ws[(size_t)(ch + 2) * (2 * NPTS) + q]);
        m3 = fminf(m3, ws[(size_t)(ch + 3) * (2 * NPTS) + q]);
    }
    float s = sqrtf(fminf(fminf(m0, m1), fminf(m2, m3)));

#pragma unroll
    for (int off = 32; off > 0; off >>= 1)
        s += __shfl_down(s, off, 64);

    if ((threadIdx.x & 63) == 0)
        atomicAdd(out, s);
}

extern "C" void kernel_launch(void* const* d_in, const int* in_sizes, int n_in,
                              void* d_out, int out_size, void* d_ws, size_t ws_size,
                              hipStream_t stream) {
    const float2* pc  = (const float2*)d_in[0];  // img_render_points (128*128*2 f32)
    const float2* ref = (const float2*)d_in[1];  // ref contour (16384*2 f32)
    float* out = (float*)d_out;
    float* ws  = (float*)d_ws;                   // 16 MB used

    // 2 dirs x 8 query-blocks x 128 chunks = 2048 blocks
    cc_min_kernel<<<2 * QB * TCH, BLK, 0, stream>>>(pc, ref, ws, out);
    cc_final_kernel<<<(2 * NPTS) / BLK, BLK, 0, stream>>>(ws, out);
}

// Round 2
// 93.021 us; speedup vs baseline: 1.0738x; 1.0738x over previous
//
#include <hip/hip_runtime.h>
#include <math.h>

// Both clouds: 16384 x float2.
#define NPTS  16384
#define BLK   256
#define Q     8                      // queries per thread
#define QB    (NPTS / (BLK * Q))     // 8 query-blocks per direction
#define TCH   64                     // target chunks per direction
#define CHUNK (NPTS / TCH)           // 256 targets per chunk
#define G     (CHUNK / 4)            // 64 groups of 4 targets

// ws layout (float): ws[ch][dir*NPTS + q] = per-chunk min d^2 for that query.
// TCH * 2*NPTS * 4 B = 8 MB of workspace. Every slot is written exactly once
// (block (dir,qb,ch) owns slots [ch][dir*NPTS + qb*2048 .. +2047]), so no
// init and no atomics; harness poison is overwritten before it is read.

// __launch_bounds__(256, 4): 128-VGPR budget (512/SIMD pool). The previous
// (256,6) bound capped the kernel at 85 VGPRs -- not enough for the unrolled
// target tile + 32 query regs, forcing the scheduler to shrink its pipeline
// window. 4 waves/SIMD * 4 blocks/CU = full residency for a 1024-block grid.
__global__ __launch_bounds__(BLK, 4) void cc_min_kernel(
        const float2* __restrict__ pc,    // render points (16384)
        const float2* __restrict__ ref,   // ref points    (16384)
        float* __restrict__ ws,
        float* __restrict__ out) {
    // Per 4-target group g: s6[12g..] = A(-2x0,-2y0,-2x1,-2y1),
    //                       B(-2x2,-2y2,-2x3,-2y3), C(z0,z1,z2,z3).
    // 3 broadcast ds_read_b128 per 4 targets (was 2 reads per 2 targets).
    __shared__ float s6[G * 12];     // 3 KB

    int b   = blockIdx.x;
    int dir = b / (QB * TCH);
    int rem = b % (QB * TCH);
    int qb  = rem / TCH;
    int ch  = rem % TCH;

    // Zero the output accumulator for the (stream-ordered) final kernel.
    if (b == 0 && threadIdx.x == 0) out[0] = 0.0f;

    const float2* __restrict__ qry = dir ? ref : pc;
    const float2* __restrict__ tgt = dir ? pc  : ref;

    if (threadIdx.x < G) {
        int g = threadIdx.x;
        const float4* t4 = (const float4*)tgt + (size_t)ch * (CHUNK / 2);
        float4 p01 = t4[2 * g];       // (x0, y0, x1, y1)
        float4 p23 = t4[2 * g + 1];   // (x2, y2, x3, y3)
        float4* dst = (float4*)&s6[12 * g];
        dst[0] = make_float4(-2.0f * p01.x, -2.0f * p01.y,
                             -2.0f * p01.z, -2.0f * p01.w);
        dst[1] = make_float4(-2.0f * p23.x, -2.0f * p23.y,
                             -2.0f * p23.z, -2.0f * p23.w);
        dst[2] = make_float4(fmaf(p01.x, p01.x, p01.y * p01.y),
                             fmaf(p01.z, p01.z, p01.w * p01.w),
                             fmaf(p23.x, p23.x, p23.y * p23.y),
                             fmaf(p23.z, p23.z, p23.w * p23.w));
    }

    // Q queries per thread (coalesced, stride BLK)
    float px[Q], py[Q], pn[Q], m[Q];
    int qbase = qb * (BLK * Q) + threadIdx.x;
#pragma unroll
    for (int j = 0; j < Q; ++j) {
        float2 p = qry[qbase + j * BLK];
        px[j] = p.x;
        py[j] = p.y;
        pn[j] = fmaf(p.x, p.x, p.y * p.y);
        m[j]  = INFINITY;
    }
    __syncthreads();

    // Surrogate s = |t|^2 - 2q.t.  Per 4 targets per query:
    //   8 FMA + 2 min3  =>  2.5 VALU instr / target.
#pragma unroll 4
    for (int g = 0; g < G; ++g) {
        float4 A = *(const float4*)&s6[12 * g];
        float4 B = *(const float4*)&s6[12 * g + 4];
        float4 C = *(const float4*)&s6[12 * g + 8];
#pragma unroll
        for (int j = 0; j < Q; ++j) {
            float s0 = fmaf(px[j], A.x, fmaf(py[j], A.y, C.x));
            float s1 = fmaf(px[j], A.z, fmaf(py[j], A.w, C.y));
            float s2 = fmaf(px[j], B.x, fmaf(py[j], B.y, C.z));
            float s3 = fmaf(px[j], B.z, fmaf(py[j], B.w, C.w));
            m[j] = fminf(fminf(m[j], s0), s1);   // -> v_min3_f32
            m[j] = fminf(fminf(m[j], s2), s3);   // -> v_min3_f32
        }
    }

    // d^2 = max(min_surrogate + |p|^2, 0); plain coalesced store of this
    // block's partial min -- combine happens in cc_final_kernel.
    float* wrow = ws + (size_t)ch * (2 * NPTS) + dir * NPTS + qbase;
#pragma unroll
    for (int j = 0; j < Q; ++j) {
        wrow[j * BLK] = fmaxf(m[j] + pn[j], 0.0f);
    }
}

// Parallel finish: one thread per (dir,query), 256 blocks x 128 threads.
// 16 independent accumulators -> 16 outstanding loads (latency-hiding at
// low occupancy), then tree-min, sqrt, wave reduce, one atomicAdd/wave.
#define FBLK 128
__global__ __launch_bounds__(FBLK) void cc_final_kernel(
        const float* __restrict__ ws, float* __restrict__ out) {
    int q = blockIdx.x * FBLK + threadIdx.x;   // 0 .. 2*NPTS-1

    float mm[16];
#pragma unroll
    for (int k = 0; k < 16; ++k)
        mm[k] = ws[(size_t)k * (2 * NPTS) + q];
#pragma unroll
    for (int ch = 16; ch < TCH; ch += 16) {
#pragma unroll
        for (int k = 0; k < 16; ++k)
            mm[k] = fminf(mm[k], ws[(size_t)(ch + k) * (2 * NPTS) + q]);
    }
#pragma unroll
    for (int s2 = 8; s2 > 0; s2 >>= 1)
#pragma unroll
        for (int k = 0; k < 8; ++k)
            if (k < s2) mm[k] = fminf(mm[k], mm[k + s2]);

    float s = sqrtf(mm[0]);

#pragma unroll
    for (int off = 32; off > 0; off >>= 1)
        s += __shfl_down(s, off, 64);

    if ((threadIdx.x & 63) == 0)
        atomicAdd(out, s);
}

extern "C" void kernel_launch(void* const* d_in, const int* in_sizes, int n_in,
                              void* d_out, int out_size, void* d_ws, size_t ws_size,
                              hipStream_t stream) {
    const float2* pc  = (const float2*)d_in[0];  // img_render_points (128*128*2 f32)
    const float2* ref = (const float2*)d_in[1];  // ref contour (16384*2 f32)
    float* out = (float*)d_out;
    float* ws  = (float*)d_ws;                   // 8 MB used

    // 2 dirs x 8 query-blocks x 64 chunks = 1024 blocks = 4/CU resident
    cc_min_kernel<<<2 * QB * TCH, BLK, 0, stream>>>(pc, ref, ws, out);
    cc_final_kernel<<<(2 * NPTS) / FBLK, FBLK, 0, stream>>>(ws, out);
}